// Round 2
// baseline (70.669 us; speedup 1.0000x reference)
//
#include <hip/hip_runtime.h>
#include <math.h>

// CGWeight: out[k] = nan_to_num( sum_c w[c] * sum_{i,j} CG_c[i,j,k] * A[la_c][i] * H[lh_c][j] )
// L_OUT = 2. Valid (la,lh) combos (triangle rule), in reference enumeration order:
__device__ const int C_LA[16]   = {0,1,1,1,2,2,2,2,2,3,3,3,3,4,4,4};
__device__ const int C_LH[16]   = {2,1,2,3,0,1,2,3,4,1,2,3,4,2,3,4};
// prefix sums of (2la+1)*(2lh+1) per combo (the (i,j) pair count):
__device__ const int C_END5[16] = {5,14,29,50,55,70,95,130,175,196,231,280,343,388,451,532};
#define NPAIRS 532

__device__ const double FACT[16] = {
    1.0, 1.0, 2.0, 6.0, 24.0, 120.0, 720.0, 5040.0,
    40320.0, 362880.0, 3628800.0, 39916800.0, 479001600.0,
    6227020800.0, 87178291200.0, 1307674368000.0};

struct Cplx { double re, im; };
__device__ inline Cplx cmul(Cplx a, Cplx b) {
    return {a.re * b.re - a.im * b.im, a.re * b.im + a.im * b.re};
}

// Racah formula, exactly mirroring the reference's _su2_cg.
__device__ double su2_cg(int j1, int m1, int j2, int m2, int j3, int m3) {
    if (m1 + m2 != m3) return 0.0;
    int vmin = max(max(-j1 + j2 + m3, -j1 + m1), 0);
    int vmax = min(min(j2 + j3 + m1, j3 - j1 + j2), j3 + m3);
    if (vmax < vmin) return 0.0;
    double C = sqrt((2.0 * j3 + 1.0)
                    * FACT[j3 + j1 - j2] * FACT[j3 - j1 + j2] * FACT[j1 + j2 - j3]
                    / FACT[j1 + j2 + j3 + 1]
                    * FACT[j3 + m3] * FACT[j3 - m3]
                    / (FACT[j1 + m1] * FACT[j1 - m1] * FACT[j2 + m2] * FACT[j2 - m2]));
    double S = 0.0;
    for (int v = vmin; v <= vmax; ++v) {
        double t = FACT[j2 + j3 + m1 - v] * FACT[j1 - m1 + v]
                 / (FACT[v] * FACT[j3 - j1 + j2 - v] * FACT[j3 + m3 - v] * FACT[v + j1 - j2 - m3]);
        S += ((v + j2 + m2) & 1) ? -t : t;
    }
    return C * S;
}

// Nonzero rows of column c of the e3nn real->complex basis matrix Q_l.
// Returns count (1 or 2); rows[] are su2 row indices, vals[] = Q[row][c].
__device__ int q_col(int l, int c, int rows[2], Cplx vals[2]) {
    Cplx ph;                                  // (-i)^l
    switch (l & 3) {
        case 0: ph = { 1.0,  0.0}; break;
        case 1: ph = { 0.0, -1.0}; break;
        case 2: ph = {-1.0,  0.0}; break;
        default: ph = { 0.0,  1.0}; break;
    }
    const double is2 = 0.70710678118654752440;
    int mu = c - l;
    if (mu == 0) { rows[0] = l; vals[0] = ph; return 1; }
    int amu = mu > 0 ? mu : -mu;
    double sgn = (amu & 1) ? -1.0 : 1.0;      // (-1)^|mu|
    rows[0] = l - amu;
    rows[1] = l + amu;
    if (mu > 0) {                             // column l+|mu|
        vals[0] = cmul(ph, {is2, 0.0});       // from m=-|mu| row
        vals[1] = cmul(ph, {sgn * is2, 0.0}); // from m=+|mu| row
    } else {                                  // column l-|mu|
        vals[0] = cmul(ph, {0.0, -is2});
        vals[1] = cmul(ph, {0.0, sgn * is2});
    }
    return 2;
}

// Real-basis CG element:
//   CG[ja, jh, ko] = sum_{i,k,n} Q1[i,ja] Q2[k,jh] conj(Q3[n,ko]) Csu2[i,k,n]
// v3 holds the UN-conjugated Q3[n,ko]; the dot-product form
//   t.re*v3.re + t.im*v3.im == Re(t * conj(v3))
// implements the conjugation. (R0 bug: caller conjugated v3 AND used this
// form -> double conj -> sign flip on complex contributions.)
__device__ double cg_real(int l1, int ja, int l2, int jh,
                          const int r3[2], const Cplx v3[2], int n3, int l3) {
    int r1[2], r2[2];
    Cplx v1[2], v2[2];
    int n1 = q_col(l1, ja, r1, v1);
    int n2 = q_col(l2, jh, r2, v2);
    double acc = 0.0;
    for (int a = 0; a < n1; ++a)
        for (int b = 0; b < n2; ++b)
            for (int cidx = 0; cidx < n3; ++cidx) {
                int m1 = r1[a] - l1, m2 = r2[b] - l2, m3 = r3[cidx] - l3;
                if (m1 + m2 != m3) continue;
                double cg = su2_cg(l1, m1, l2, m2, l3, m3);
                if (cg == 0.0) continue;
                Cplx t = cmul(v1[a], v2[b]);
                acc += (t.re * v3[cidx].re + t.im * v3[cidx].im) * cg; // Re(t*conj(v3))
            }
    return acc;
}

__global__ __launch_bounds__(256) void cgweight_kernel(
    const float* __restrict__ a0, const float* __restrict__ a1,
    const float* __restrict__ a2, const float* __restrict__ a3,
    const float* __restrict__ a4,
    const float* __restrict__ h0, const float* __restrict__ h1,
    const float* __restrict__ h2, const float* __restrict__ h3,
    const float* __restrict__ h4,
    const float* __restrict__ w, float* __restrict__ out) {

    const float* A[5] = {a0, a1, a2, a3, a4};
    const float* H[5] = {h0, h1, h2, h3, h4};

    double acc0 = 0.0, acc1 = 0.0, acc2 = 0.0, acc3 = 0.0, acc4 = 0.0;

    for (int e = threadIdx.x; e < NPAIRS; e += 256) {
        int c = 0;
        while (e >= C_END5[c]) ++c;
        int start = (c == 0) ? 0 : C_END5[c - 1];
        int local = e - start;
        int la = C_LA[c], lh = C_LH[c];
        int Nh = 2 * lh + 1;
        int i = local / Nh;
        int j = local - i * Nh;

        double ahw = (double)A[la][i] * (double)H[lh][j] * (double)w[c];

        // k = 0..4 unrolled, static accumulator indices (no scratch).
        // NOTE: v3 passed UN-conjugated; cg_real's dot form applies conj.
        {
            int r3[2]; Cplx v3[2];
            int n3 = q_col(2, 0, r3, v3);
            acc0 += cg_real(la, i, lh, j, r3, v3, n3, 2) * ahw;
        }
        {
            int r3[2]; Cplx v3[2];
            int n3 = q_col(2, 1, r3, v3);
            acc1 += cg_real(la, i, lh, j, r3, v3, n3, 2) * ahw;
        }
        {
            int r3[2]; Cplx v3[2];
            int n3 = q_col(2, 2, r3, v3);
            acc2 += cg_real(la, i, lh, j, r3, v3, n3, 2) * ahw;
        }
        {
            int r3[2]; Cplx v3[2];
            int n3 = q_col(2, 3, r3, v3);
            acc3 += cg_real(la, i, lh, j, r3, v3, n3, 2) * ahw;
        }
        {
            int r3[2]; Cplx v3[2];
            int n3 = q_col(2, 4, r3, v3);
            acc4 += cg_real(la, i, lh, j, r3, v3, n3, 2) * ahw;
        }
    }

    // wave (64-lane) butterfly reduction for each accumulator
    double acc[5] = {acc0, acc1, acc2, acc3, acc4};
#pragma unroll
    for (int k = 0; k < 5; ++k) {
        double v = acc[k];
#pragma unroll
        for (int off = 32; off > 0; off >>= 1)
            v += __shfl_down(v, off, 64);
        acc[k] = v;
    }

    __shared__ double sred[4][5];
    int wave = threadIdx.x >> 6;
    int lane = threadIdx.x & 63;
    if (lane == 0) {
#pragma unroll
        for (int k = 0; k < 5; ++k) sred[wave][k] = acc[k];
    }
    __syncthreads();

    if (threadIdx.x == 0) {
#pragma unroll
        for (int k = 0; k < 5; ++k) {
            double v = sred[0][k] + sred[1][k] + sred[2][k] + sred[3][k];
            float f = (float)v;
            out[k] = (f != f) ? 0.0f : f;  // nan_to_num
        }
    }
}

extern "C" void kernel_launch(void* const* d_in, const int* in_sizes, int n_in,
                              void* d_out, int out_size, void* d_ws, size_t ws_size,
                              hipStream_t stream) {
    const float* a0 = (const float*)d_in[0];
    const float* a1 = (const float*)d_in[1];
    const float* a2 = (const float*)d_in[2];
    const float* a3 = (const float*)d_in[3];
    const float* a4 = (const float*)d_in[4];
    const float* h0 = (const float*)d_in[5];
    const float* h1 = (const float*)d_in[6];
    const float* h2 = (const float*)d_in[7];
    const float* h3 = (const float*)d_in[8];
    const float* h4 = (const float*)d_in[9];
    const float* w  = (const float*)d_in[10];
    float* out = (float*)d_out;

    cgweight_kernel<<<1, 256, 0, stream>>>(a0, a1, a2, a3, a4,
                                           h0, h1, h2, h3, h4, w, out);
}

// Round 3
// 9.828 us; speedup vs baseline: 7.1905x; 7.1905x over previous
//
#include <hip/hip_runtime.h>

// CGWeight: out[k] = nan_to_num( sum_c w[c] * sum_{i,j} CG_c[i,j,k] * A[la_c][i] * H[lh_c][j] )
// L_OUT = 2. ALL Clebsch-Gordan math is done at COMPILE TIME via constexpr;
// runtime is a single 64-lane wave doing ~9 iterations of f32 FMAs.

namespace cgc {

constexpr int C_LA[16] = {0,1,1,1,2,2,2,2,2,3,3,3,3,4,4,4};
constexpr int C_LH[16] = {2,1,2,3,0,1,2,3,4,1,2,3,4,2,3,4};
constexpr int ABASE[5] = {0,1,4,9,16};   // prefix offsets of concatenated l=0..4 vectors (sizes 1,3,5,7,9)

constexpr double FACT[16] = {
    1.0, 1.0, 2.0, 6.0, 24.0, 120.0, 720.0, 5040.0,
    40320.0, 362880.0, 3628800.0, 39916800.0, 479001600.0,
    6227020800.0, 87178291200.0, 1307674368000.0};

// constexpr sqrt: range-reduce to [0.25,4), 10 Newton steps (quadratic -> exact to double)
constexpr double csqrt(double x) {
    if (x <= 0.0) return 0.0;
    double s = 1.0, v = x;
    while (v > 4.0)  { v *= 0.25; s *= 2.0; }
    while (v < 0.25) { v *= 4.0;  s *= 0.5; }
    double g = 1.0;
    for (int i = 0; i < 10; ++i) g = 0.5 * (g + v / g);
    return g * s;
}

// Racah formula (mirrors reference _su2_cg)
constexpr double su2cg(int j1, int m1, int j2, int m2, int j3, int m3) {
    if (m1 + m2 != m3) return 0.0;
    int vmin = -j1 + j2 + m3; if (-j1 + m1 > vmin) vmin = -j1 + m1; if (vmin < 0) vmin = 0;
    int vmax = j2 + j3 + m1; if (j3 - j1 + j2 < vmax) vmax = j3 - j1 + j2; if (j3 + m3 < vmax) vmax = j3 + m3;
    if (vmax < vmin) return 0.0;
    double C = csqrt((2.0 * j3 + 1.0)
                     * FACT[j3 + j1 - j2] * FACT[j3 - j1 + j2] * FACT[j1 + j2 - j3]
                     / FACT[j1 + j2 + j3 + 1]
                     * FACT[j3 + m3] * FACT[j3 - m3]
                     / (FACT[j1 + m1] * FACT[j1 - m1] * FACT[j2 + m2] * FACT[j2 - m2]));
    double S = 0.0;
    for (int v = vmin; v <= vmax; ++v) {
        double t = FACT[j2 + j3 + m1 - v] * FACT[j1 - m1 + v]
                 / (FACT[v] * FACT[j3 - j1 + j2 - v] * FACT[j3 + m3 - v] * FACT[v + j1 - j2 - m3]);
        S += ((v + j2 + m2) & 1) ? -t : t;
    }
    return C * S;
}

struct CD { double re, im; };
constexpr CD cmul(CD a, CD b) { return {a.re*b.re - a.im*b.im, a.re*b.im + a.im*b.re}; }

// Nonzero rows of column c of the e3nn real->complex basis matrix Q_l (verified in R2 run, absmax 0.0).
constexpr int q_col(int l, int c, int* rows, CD* vals) {
    CD ph{1.0, 0.0};                           // (-i)^l
    switch (l & 3) {
        case 0: ph = { 1.0,  0.0}; break;
        case 1: ph = { 0.0, -1.0}; break;
        case 2: ph = {-1.0,  0.0}; break;
        default: ph = { 0.0,  1.0}; break;
    }
    const double is2 = 0.70710678118654752440;
    int mu = c - l;
    if (mu == 0) { rows[0] = l; vals[0] = ph; return 1; }
    int amu = mu > 0 ? mu : -mu;
    double sgn = (amu & 1) ? -1.0 : 1.0;       // (-1)^|mu|
    rows[0] = l - amu;
    rows[1] = l + amu;
    if (mu > 0) {
        vals[0] = cmul(ph, {is2, 0.0});
        vals[1] = cmul(ph, {sgn * is2, 0.0});
    } else {
        vals[0] = cmul(ph, {0.0, -is2});
        vals[1] = cmul(ph, {0.0, sgn * is2});
    }
    return 2;
}

#define MAXE 532
struct Tables {
    int n;
    short aoff[MAXE];
    short hoff[MAXE];
    short wi[MAXE];
    float cg[MAXE][5];
};

constexpr Tables build() {
    Tables T{};
    // Q3 columns for l=2, k=0..4 (hoisted)
    int r3[5][2]{}; CD v3[5][2]{}; int n3[5]{};
    for (int k = 0; k < 5; ++k) n3[k] = q_col(2, k, r3[k], v3[k]);
    int e = 0;
    for (int c = 0; c < 16; ++c) {
        const int la = C_LA[c], lh = C_LH[c];
        // per-combo SU(2) CG table: stab[i1][i2] = <la m1 lh m2 | 2 m1+m2>
        double stab[9][9]{};
        for (int i1 = 0; i1 < 2*la+1; ++i1)
            for (int i2 = 0; i2 < 2*lh+1; ++i2) {
                int m1 = i1 - la, m2 = i2 - lh, m3 = m1 + m2;
                if (m3 >= -2 && m3 <= 2) stab[i1][i2] = su2cg(la, m1, lh, m2, 2, m3);
            }
        for (int i = 0; i < 2*la+1; ++i) {
            int r1[2]{}; CD v1[2]{}; const int n1 = q_col(la, i, r1, v1);
            for (int j = 0; j < 2*lh+1; ++j) {
                int r2[2]{}; CD v2[2]{}; const int n2 = q_col(lh, j, r2, v2);
                double outk[5]{};
                bool any = false;
                for (int k = 0; k < 5; ++k) {
                    double acc = 0.0;
                    for (int a = 0; a < n1; ++a)
                        for (int b = 0; b < n2; ++b) {
                            const int m3 = (r1[a] - la) + (r2[b] - lh);
                            for (int q = 0; q < n3[k]; ++q) {
                                if (r3[k][q] - 2 != m3) continue;
                                CD t = cmul(v1[a], v2[b]);
                                // Re(Q1*Q2*conj(Q3)) * su2cg  (conj via + dot form)
                                acc += (t.re * v3[k][q].re + t.im * v3[k][q].im)
                                       * stab[r1[a]][r2[b]];
                            }
                        }
                    outk[k] = acc;
                    if (acc != 0.0) any = true;
                }
                if (any) {   // compact: drop all-zero (i,j) pairs
                    T.aoff[e] = (short)(ABASE[la] + i);
                    T.hoff[e] = (short)(ABASE[lh] + j);
                    T.wi[e]   = (short)c;
                    for (int k = 0; k < 5; ++k) T.cg[e][k] = (float)outk[k];
                    ++e;
                }
            }
        }
    }
    T.n = e;
    return T;
}

} // namespace cgc

__constant__ cgc::Tables g_tab = cgc::build();

__global__ __launch_bounds__(64) void cgweight_kernel(
    const float* __restrict__ a0, const float* __restrict__ a1,
    const float* __restrict__ a2, const float* __restrict__ a3,
    const float* __restrict__ a4,
    const float* __restrict__ h0, const float* __restrict__ h1,
    const float* __restrict__ h2, const float* __restrict__ h3,
    const float* __restrict__ h4,
    const float* __restrict__ w, float* __restrict__ out) {

    __shared__ float sA[25], sH[25], sW[16];
    const float* A[5] = {a0, a1, a2, a3, a4};
    const float* H[5] = {h0, h1, h2, h3, h4};
    const int END[5] = {1, 4, 9, 16, 25};

    const int t = threadIdx.x;   // 64 lanes, one wave
    if (t < 25) {
        int l = 0;
        while (l < 4 && t >= END[l]) ++l;
        sA[t] = A[l][t - (END[l] - (2*l+1))];
    } else if (t < 50) {
        int u = t - 25;
        int l = 0;
        while (l < 4 && u >= END[l]) ++l;
        sH[u] = H[l][u - (END[l] - (2*l+1))];
    }
    if (t >= 48) sW[t - 48] = w[t - 48];   // 16 combo weights
    __syncthreads();

    float c0 = 0.f, c1 = 0.f, c2 = 0.f, c3 = 0.f, c4 = 0.f;
    const int n = g_tab.n;
    for (int e = t; e < n; e += 64) {
        const float p = sA[g_tab.aoff[e]] * sH[g_tab.hoff[e]] * sW[g_tab.wi[e]];
        c0 += g_tab.cg[e][0] * p;
        c1 += g_tab.cg[e][1] * p;
        c2 += g_tab.cg[e][2] * p;
        c3 += g_tab.cg[e][3] * p;
        c4 += g_tab.cg[e][4] * p;
    }

    // 64-lane butterfly reduce
    float acc[5] = {c0, c1, c2, c3, c4};
#pragma unroll
    for (int k = 0; k < 5; ++k) {
        float v = acc[k];
#pragma unroll
        for (int off = 32; off > 0; off >>= 1)
            v += __shfl_down(v, off, 64);
        acc[k] = v;
    }

    if (t == 0) {
#pragma unroll
        for (int k = 0; k < 5; ++k) {
            float f = acc[k];
            out[k] = (f != f) ? 0.0f : f;   // nan_to_num
        }
    }
}

extern "C" void kernel_launch(void* const* d_in, const int* in_sizes, int n_in,
                              void* d_out, int out_size, void* d_ws, size_t ws_size,
                              hipStream_t stream) {
    const float* a0 = (const float*)d_in[0];
    const float* a1 = (const float*)d_in[1];
    const float* a2 = (const float*)d_in[2];
    const float* a3 = (const float*)d_in[3];
    const float* a4 = (const float*)d_in[4];
    const float* h0 = (const float*)d_in[5];
    const float* h1 = (const float*)d_in[6];
    const float* h2 = (const float*)d_in[7];
    const float* h3 = (const float*)d_in[8];
    const float* h4 = (const float*)d_in[9];
    const float* w  = (const float*)d_in[10];
    float* out = (float*)d_out;

    cgweight_kernel<<<1, 64, 0, stream>>>(a0, a1, a2, a3, a4,
                                          h0, h1, h2, h3, h4, w, out);
}